// Round 16
// baseline (70.071 us; speedup 1.0000x reference)
//
#include <hip/hip_runtime.h>
#include <hip/hip_bf16.h>

#define T_TOTAL 200000
#define T_PAD   200192            // 782 * 256 (padded rows; tail t harmless)
#define STEPF   (999.0f / 199999.0f)

typedef float v4f __attribute__((ext_vector_type(4)));

// Parameter quads {ww', ph'+0.25, C=2cos(wr*step), extra}, phases in
// REVOLUTIONS so sin(theta) = cos(2*pi*(fract(rev)-0.5)) (even poly).
// C is the Chebyshev coefficient for CONSECUTIVE t (stride 1 in t).
// L0: [4n]                n<20, extra = A0      [0,80)
// L1: [80  + 4*(m*20+n)]  m<25, n<20            [80,2080)
// L2: [2080 + 4*(m*25+n)] m<30, n<25            [2080,5080)
// L3: [5080 + 4m]         m<30                  [5080,5200)
__device__ float g_P[5200];
// Inter-kernel s1[m][t] buffer (padded rows): 25 x 200192 = 20 MB.
__device__ float g_s1[25 * T_PAD];
// Layer-2/3 partial sums per m-half: [half][t].
__device__ float g_part[2 * T_PAD];

// sin(2*pi*rev) via even poly: cos(2*pi*h), h = fract(rev)-0.5. |err| ~= 4e-5.
__device__ __forceinline__ float sinp(float rev) {
    float g = __builtin_amdgcn_fractf(rev);
    float h = g - 0.5f;
    float u = h * h;
    float p = fmaf(45.621248f, u, -82.391040f);
    p = fmaf(p, u, 64.671616f);
    p = fmaf(p, u, -19.730960f);
    p = fmaf(p, u, 0.9999618f);
    return p;
}

__global__ void prep_kernel(
    const float* __restrict__ A0,
    const float* __restrict__ w0, const float* __restrict__ phi0,
    const float* __restrict__ wc0, const float* __restrict__ phic0,
    const float* __restrict__ w1, const float* __restrict__ phi1,
    const float* __restrict__ wc1, const float* __restrict__ phic1,
    const float* __restrict__ w2, const float* __restrict__ phi2,
    const float* __restrict__ wc2, const float* __restrict__ phic2,
    const float* __restrict__ w3, const float* __restrict__ phi3,
    const float* __restrict__ wc3, const float* __restrict__ phic3)
{
    const int tid = blockIdx.x * blockDim.x + threadIdx.x;
    const int stride = blockDim.x * gridDim.x;

    const double I2PI = 0.15915494309189535;
    const double D1   = 999.0 / 199999.0;          // t-step (consecutive t)

    const double ws0 = fmax((double)wc0[0], 0.0), ps0 = fmax((double)phic0[0], 0.0);
    const double ws1 = fmax((double)wc1[0], 0.0), ps1 = fmax((double)phic1[0], 0.0);
    const double ws2 = fmax((double)wc2[0], 0.0), ps2 = fmax((double)phic2[0], 0.0);
    const double ws3 = fmax((double)wc3[0], 0.0), ps3 = fmax((double)phic3[0], 0.0);

    for (int n = tid; n < 20; n += stride) {
        double wr = fmax((double)w0[n], 0.0) + ws0;
        g_P[4 * n]     = (float)(wr * I2PI);
        g_P[4 * n + 1] = (float)((fmax((double)phi0[n], 0.0) + ps0) * I2PI + 0.25);
        g_P[4 * n + 2] = (float)(2.0 * cos(wr * D1));
        g_P[4 * n + 3] = A0[n];
    }
    for (int k = tid; k < 25 * 20; k += stride) {   // k = m*20+n
        double wr = fmax((double)w1[k], 0.0) + ws1;
        g_P[80 + 4 * k]     = (float)(wr * I2PI);
        g_P[80 + 4 * k + 1] = (float)((fmax((double)phi1[k], 0.0) + ps1) * I2PI + 0.25);
        g_P[80 + 4 * k + 2] = (float)(2.0 * cos(wr * D1));
        g_P[80 + 4 * k + 3] = 0.0f;
    }
    for (int k = tid; k < 30 * 25; k += stride) {   // k = m*25+n
        double wr = fmax((double)w2[k], 0.0) + ws2;
        g_P[2080 + 4 * k]     = (float)(wr * I2PI);
        g_P[2080 + 4 * k + 1] = (float)((fmax((double)phi2[k], 0.0) + ps2) * I2PI + 0.25);
        g_P[2080 + 4 * k + 2] = (float)(2.0 * cos(wr * D1));
        g_P[2080 + 4 * k + 3] = 0.0f;
    }
    for (int m = tid; m < 30; m += stride) {
        double wr = fmax((double)w3[m], 0.0) + ws3;
        g_P[5080 + 4 * m]     = (float)(wr * I2PI);
        g_P[5080 + 4 * m + 1] = (float)((fmax((double)phi3[m], 0.0) + ps3) * I2PI + 0.25);
        g_P[5080 + 4 * m + 2] = (float)(2.0 * cos(wr * D1));
        g_P[5080 + 4 * m + 3] = 0.0f;
    }
}

// Kernel A: layers 0+1 (unchanged from R15; measured ~14 us, ~80% eff).
// 782 blocks x 256 threads (4 waves); lane l owns t = tb+4l+j, j<4
// (j=0,1 direct poly; j=2,3 Chebyshev x_{j+1} = C*x_j - x_{j-1}).
__launch_bounds__(256)
__global__ void k_l01()
{
    __shared__ float pp[2000];       // L1 quads (8000 B)
    __shared__ float s0s[20 * 256];  // s0[n][t_local] (20480 B)

    const int tid = threadIdx.x;
    for (int i = tid; i < 2000; i += 256) pp[i] = g_P[80 + i];

    const int l = tid & 63;
    const int w = __builtin_amdgcn_readfirstlane(tid >> 6);
    const int tb = blockIdx.x * 256;
    const int tl = 4 * l;
    const float tv0 = fmaf((float)(tb + tl), STEPF, 1.0f);
    const float tv1 = tv0 + STEPF;

    // layer 0: wave w computes n = 5w..5w+4
#pragma unroll
    for (int i = 0; i < 5; ++i) {
        const int n = 5 * w + i;
        const v4f q = *(const v4f*)&g_P[4 * n];
        float x0 = q[3] * sinp(fmaf(q[0], tv0, q[1]));
        float x1 = q[3] * sinp(fmaf(q[0], tv1, q[1]));
        float x2 = fmaf(q[2], x1, -x0);
        float x3 = fmaf(q[2], x2, -x1);
        *(v4f*)&s0s[n * 256 + tl] = (v4f){x0, x1, x2, x3};
    }
    __syncthreads();

    float sum0[4] = {0.f, 0.f, 0.f, 0.f};
#pragma unroll
    for (int n = 0; n < 20; ++n) {
        const v4f s = *(const v4f*)&s0s[n * 256 + tl];
        sum0[0] += s[0]; sum0[1] += s[1]; sum0[2] += s[2]; sum0[3] += s[3];
    }

    const int mS = w ? (1 + 6 * w) : 0;          // 7,6,6,6 of 25
    const int mC = w ? 6 : 7;
    for (int i = 0; i < mC; ++i) {
        const int m = mS + i;
        const float* __restrict__ pb = &pp[80 * m];
        float a0 = 0.f, a1 = 0.f, a2 = 0.f, a3 = 0.f;
#pragma unroll
        for (int n = 0; n < 20; ++n) {
            const v4f q = *(const v4f*)&pb[4 * n];           // uniform b128
            const v4f s = *(const v4f*)&s0s[n * 256 + tl];   // per-lane b128
            float x0 = sinp(fmaf(q[0], tv0, q[1]));
            float x1 = sinp(fmaf(q[0], tv1, q[1]));
            float x2 = fmaf(q[2], x1, -x0);
            float x3 = fmaf(q[2], x2, -x1);
            a0 = fmaf(x0, s[0], a0);
            a1 = fmaf(x1, s[1], a1);
            a2 = fmaf(x2, s[2], a2);
            a3 = fmaf(x3, s[3], a3);
        }
        const v4f o = {fmaf(0.5f, a0, 0.5f * sum0[0]),
                       fmaf(0.5f, a1, 0.5f * sum0[1]),
                       fmaf(0.5f, a2, 0.5f * sum0[2]),
                       fmaf(0.5f, a3, 0.5f * sum0[3])};
        *(v4f*)&g_s1[m * T_PAD + tb + tl] = o;               // dwordx4 store
    }
}

// Kernel B: layers 2+3, m-SPLIT ACROSS BLOCK PAIRS. Block pair (2b,2b+1)
// covers the same 256 t; half h owns m in [15h, 15h+15). s1 is read
// DIRECTLY from global inside the loops (dwordx4; first pass warms L1,
// later m-iterations hit L1) - the R12-B property that measured 88% busy -
// and the grid has 1564 blocks = 6256 waves for latency hiding. Tiny LDS
// (10.3 KB): params + 4-wave reduce. Partials go to g_part[half][t].
__launch_bounds__(256)
__global__ void k_l23()
{
    __shared__ float pp[1560];       // 15 m x 100 L2 quads + 15 L3 quads
    __shared__ float shp[4 * 256];   // cross-wave partial reduce

    const int tid = threadIdx.x;
    const int half = blockIdx.x & 1;
    const int tb = (blockIdx.x >> 1) * 256;

    for (int i = tid; i < 1560; i += 256)
        pp[i] = (i < 1500) ? g_P[2080 + 1500 * half + i]
                           : g_P[5080 + 60 * half + (i - 1500)];

    const int l = tid & 63;
    const int w = __builtin_amdgcn_readfirstlane(tid >> 6);
    const int tl = 4 * l;
    const float tv0 = fmaf((float)(tb + tl), STEPF, 1.0f);
    const float tv1 = tv0 + STEPF;

    // sum over n of s1 (also warms L1 with the 25.6 KB tile)
    float sum1[4] = {0.f, 0.f, 0.f, 0.f};
#pragma unroll
    for (int n = 0; n < 25; ++n) {
        const v4f s = *(const v4f*)&g_s1[n * T_PAD + tb + tl];
        sum1[0] += s[0]; sum1[1] += s[1]; sum1[2] += s[2]; sum1[3] += s[3];
    }
    __syncthreads();

    // wave w owns local m = 4w..4w+mC-1 (4,4,4,3 of 15)
    const int mS = 4 * w;
    const int mC = (w == 3) ? 3 : 4;
    float pw0 = 0.f, pw1 = 0.f, pw2 = 0.f, pw3 = 0.f;
    for (int i = 0; i < mC; ++i) {
        const int lm = mS + i;
        const float* __restrict__ pb = &pp[100 * lm];
        float a0 = 0.f, a1 = 0.f, a2 = 0.f, a3 = 0.f;
#pragma unroll
        for (int n = 0; n < 25; ++n) {
            const v4f q = *(const v4f*)&pb[4 * n];             // uniform b128
            const v4f s = *(const v4f*)&g_s1[n * T_PAD + tb + tl]; // L1-hit x4
            float x0 = sinp(fmaf(q[0], tv0, q[1]));
            float x1 = sinp(fmaf(q[0], tv1, q[1]));
            float x2 = fmaf(q[2], x1, -x0);
            float x3 = fmaf(q[2], x2, -x1);
            a0 = fmaf(x0, s[0], a0);
            a1 = fmaf(x1, s[1], a1);
            a2 = fmaf(x2, s[2], a2);
            a3 = fmaf(x3, s[3], a3);
        }
        // layer 3 term for this m
        const v4f q3 = *(const v4f*)&pp[1500 + 4 * lm];
        float y0 = sinp(fmaf(q3[0], tv0, q3[1]));
        float y1 = sinp(fmaf(q3[0], tv1, q3[1]));
        float y2 = fmaf(q3[2], y1, -y0);
        float y3 = fmaf(q3[2], y2, -y1);
        pw0 = fmaf(fmaf(0.5f, y0, 0.5f), fmaf(0.5f, a0, 0.5f * sum1[0]), pw0);
        pw1 = fmaf(fmaf(0.5f, y1, 0.5f), fmaf(0.5f, a1, 0.5f * sum1[1]), pw1);
        pw2 = fmaf(fmaf(0.5f, y2, 0.5f), fmaf(0.5f, a2, 0.5f * sum1[2]), pw2);
        pw3 = fmaf(fmaf(0.5f, y3, 0.5f), fmaf(0.5f, a3, 0.5f * sum1[3]), pw3);
    }
    *(v4f*)&shp[w * 256 + tl] = (v4f){pw0, pw1, pw2, pw3};
    __syncthreads();

    // reduce across the 4 waves; wave w writes t_local in [64w, 64w+64)
    const int tlr = 64 * w + l;
    const float r = (shp[tlr] + shp[256 + tlr]) + (shp[512 + tlr] + shp[768 + tlr]);
    g_part[half * T_PAD + tb + tlr] = r;
}

// Combiner: out[t] = part0[t] + part1[t]. Deterministic, fully parallel.
__launch_bounds__(256)
__global__ void k_comb(float* __restrict__ out)
{
    const int t = blockIdx.x * 256 + threadIdx.x;
    if (t < T_TOTAL) out[t] = g_part[t] + g_part[T_PAD + t];
}

extern "C" void kernel_launch(void* const* d_in, const int* in_sizes, int n_in,
                              void* d_out, int out_size, void* d_ws, size_t ws_size,
                              hipStream_t stream) {
    (void)in_sizes; (void)n_in; (void)d_ws; (void)ws_size; (void)out_size;
    const float* A0    = (const float*)d_in[1];
    const float* w0    = (const float*)d_in[2];
    const float* phi0  = (const float*)d_in[3];
    const float* wc0   = (const float*)d_in[4];
    const float* phic0 = (const float*)d_in[5];
    const float* w1    = (const float*)d_in[6];
    const float* phi1  = (const float*)d_in[7];
    const float* wc1   = (const float*)d_in[8];
    const float* phic1 = (const float*)d_in[9];
    const float* w2    = (const float*)d_in[10];
    const float* phi2  = (const float*)d_in[11];
    const float* wc2   = (const float*)d_in[12];
    const float* phic2 = (const float*)d_in[13];
    const float* w3    = (const float*)d_in[14];
    const float* phi3  = (const float*)d_in[15];
    const float* wc3   = (const float*)d_in[16];
    const float* phic3 = (const float*)d_in[17];

    float* out = (float*)d_out;

    hipLaunchKernelGGL(prep_kernel, dim3(6), dim3(256), 0, stream,
                       A0, w0, phi0, wc0, phic0,
                       w1, phi1, wc1, phic1,
                       w2, phi2, wc2, phic2,
                       w3, phi3, wc3, phic3);

    const int grid = (T_TOTAL + 255) / 256;   // 782
    hipLaunchKernelGGL(k_l01, dim3(grid), dim3(256), 0, stream);
    hipLaunchKernelGGL(k_l23, dim3(2 * grid), dim3(256), 0, stream);
    hipLaunchKernelGGL(k_comb, dim3(grid), dim3(256), 0, stream, out);
}

// Round 17
// 57.596 us; speedup vs baseline: 1.2166x; 1.2166x over previous
//
#include <hip/hip_runtime.h>
#include <hip/hip_bf16.h>

#define T_TOTAL 200000
#define STEPF   (999.0f / 199999.0f)

typedef float v4f __attribute__((ext_vector_type(4)));

// Parameter quads {ww', ph'+0.25, C=2cos(wr*step), extra}, phases in
// REVOLUTIONS so sin(theta) = cos(2*pi*(fract(rev)-0.5)) (even poly).
// C is the Chebyshev coefficient for CONSECUTIVE t (stride 1).
// L0: [4n]                n<20, extra = A0      [0,80)
// L1: [80  + 4*(m*20+n)]  m<25, n<20            [80,2080)
// L2: [2080 + 4*(m*25+n)] m<30, n<25            [2080,5080)
// L3: [5080 + 4m]         m<30                  [5080,5200)
__device__ float g_P[5200];

// sin(2*pi*rev) via even poly: cos(2*pi*h), h = fract(rev)-0.5. |err| ~= 4e-5.
__device__ __forceinline__ float sinp(float rev) {
    float g = __builtin_amdgcn_fractf(rev);
    float h = g - 0.5f;
    float u = h * h;
    float p = fmaf(45.621248f, u, -82.391040f);
    p = fmaf(p, u, 64.671616f);
    p = fmaf(p, u, -19.730960f);
    p = fmaf(p, u, 0.9999618f);
    return p;
}

__global__ void prep_kernel(
    const float* __restrict__ A0,
    const float* __restrict__ w0, const float* __restrict__ phi0,
    const float* __restrict__ wc0, const float* __restrict__ phic0,
    const float* __restrict__ w1, const float* __restrict__ phi1,
    const float* __restrict__ wc1, const float* __restrict__ phic1,
    const float* __restrict__ w2, const float* __restrict__ phi2,
    const float* __restrict__ wc2, const float* __restrict__ phic2,
    const float* __restrict__ w3, const float* __restrict__ phi3,
    const float* __restrict__ wc3, const float* __restrict__ phic3)
{
    const int tid = blockIdx.x * blockDim.x + threadIdx.x;
    const int stride = blockDim.x * gridDim.x;

    const double I2PI = 0.15915494309189535;
    const double D1   = 999.0 / 199999.0;          // t-step (consecutive t)

    const double ws0 = fmax((double)wc0[0], 0.0), ps0 = fmax((double)phic0[0], 0.0);
    const double ws1 = fmax((double)wc1[0], 0.0), ps1 = fmax((double)phic1[0], 0.0);
    const double ws2 = fmax((double)wc2[0], 0.0), ps2 = fmax((double)phic2[0], 0.0);
    const double ws3 = fmax((double)wc3[0], 0.0), ps3 = fmax((double)phic3[0], 0.0);

    for (int n = tid; n < 20; n += stride) {
        double wr = fmax((double)w0[n], 0.0) + ws0;
        g_P[4 * n]     = (float)(wr * I2PI);
        g_P[4 * n + 1] = (float)((fmax((double)phi0[n], 0.0) + ps0) * I2PI + 0.25);
        g_P[4 * n + 2] = (float)(2.0 * cos(wr * D1));
        g_P[4 * n + 3] = A0[n];
    }
    for (int k = tid; k < 25 * 20; k += stride) {   // k = m*20+n
        double wr = fmax((double)w1[k], 0.0) + ws1;
        g_P[80 + 4 * k]     = (float)(wr * I2PI);
        g_P[80 + 4 * k + 1] = (float)((fmax((double)phi1[k], 0.0) + ps1) * I2PI + 0.25);
        g_P[80 + 4 * k + 2] = (float)(2.0 * cos(wr * D1));
        g_P[80 + 4 * k + 3] = 0.0f;
    }
    for (int k = tid; k < 30 * 25; k += stride) {   // k = m*25+n
        double wr = fmax((double)w2[k], 0.0) + ws2;
        g_P[2080 + 4 * k]     = (float)(wr * I2PI);
        g_P[2080 + 4 * k + 1] = (float)((fmax((double)phi2[k], 0.0) + ps2) * I2PI + 0.25);
        g_P[2080 + 4 * k + 2] = (float)(2.0 * cos(wr * D1));
        g_P[2080 + 4 * k + 3] = 0.0f;
    }
    for (int m = tid; m < 30; m += stride) {
        double wr = fmax((double)w3[m], 0.0) + ws3;
        g_P[5080 + 4 * m]     = (float)(wr * I2PI);
        g_P[5080 + 4 * m + 1] = (float)((fmax((double)phi3[m], 0.0) + ps3) * I2PI + 0.25);
        g_P[5080 + 4 * m + 2] = (float)(2.0 * cos(wr * D1));
        g_P[5080 + 4 * m + 3] = 0.0f;
    }
}

// Fused all-layers kernel. 782 blocks x 256 threads (4 waves); block covers
// 256 consecutive t; lane l owns t = tb+4l+j, j<4 (j=0,1 direct poly;
// j=2,3 Chebyshev x_{j+1} = C*x_j - x_{j-1}). All cross-layer vectors move
// as per-lane ds_read_b128 ([n][4l] layout, conflict-free) and params as
// uniform-broadcast b128 -- the R15-A recipe (measured ~80% eff) applied
// to the whole net. s1 NEVER leaves the CU (kills the 20MB HBM round-trip
// that pinned every split-B at ~45us). LDS phased/aliased: 54 KB.
__launch_bounds__(256)
__global__ void wave_fused(float* __restrict__ out)
{
    __shared__ float S[13520];
    float* const pp1 = S;            // [0,2000): L1 quads
    float* const s0s = S + 2000;     // [2000,7120): s0[n][tl], 20*256
    float* const s1s = S + 7120;     // [7120,13520): s1[n][tl], 25*256
    float* const pp2 = S;            // [0,3120): L2+L3 quads (alias, phase C)
    float* const shp = S + 3200;     // [3200,4224): reduce buf (alias, dead s0)

    const int tid = threadIdx.x;
    const int l = tid & 63;
    const int w = __builtin_amdgcn_readfirstlane(tid >> 6);
    const int tb = blockIdx.x * 256;
    const int tl = 4 * l;
    const float tv0 = fmaf((float)(tb + tl), STEPF, 1.0f);
    const float tv1 = tv0 + STEPF;

    // ---- phase A: stage L1 params; layer 0 (wave w: n = 5w..5w+4) ----
    for (int i = tid; i < 2000; i += 256) pp1[i] = g_P[80 + i];
#pragma unroll
    for (int i = 0; i < 5; ++i) {
        const int n = 5 * w + i;
        const v4f q = *(const v4f*)&g_P[4 * n];
        float x0 = q[3] * sinp(fmaf(q[0], tv0, q[1]));
        float x1 = q[3] * sinp(fmaf(q[0], tv1, q[1]));
        float x2 = fmaf(q[2], x1, -x0);
        float x3 = fmaf(q[2], x2, -x1);
        *(v4f*)&s0s[n * 256 + tl] = (v4f){x0, x1, x2, x3};
    }
    __syncthreads();

    // ---- phase B: sum0 + layer 1 (wave w owns 7/6/6/6 of 25 m) ----
    float sum0[4] = {0.f, 0.f, 0.f, 0.f};
#pragma unroll
    for (int n = 0; n < 20; ++n) {
        const v4f s = *(const v4f*)&s0s[n * 256 + tl];
        sum0[0] += s[0]; sum0[1] += s[1]; sum0[2] += s[2]; sum0[3] += s[3];
    }
    {
        const int mS = w ? (1 + 6 * w) : 0;
        const int mC = w ? 6 : 7;
        for (int i = 0; i < mC; ++i) {
            const int m = mS + i;
            const float* __restrict__ pb = &pp1[80 * m];
            float a0 = 0.f, a1 = 0.f, a2 = 0.f, a3 = 0.f;
#pragma unroll
            for (int n = 0; n < 20; ++n) {
                const v4f q = *(const v4f*)&pb[4 * n];           // uniform b128
                const v4f s = *(const v4f*)&s0s[n * 256 + tl];   // per-lane b128
                float x0 = sinp(fmaf(q[0], tv0, q[1]));
                float x1 = sinp(fmaf(q[0], tv1, q[1]));
                float x2 = fmaf(q[2], x1, -x0);
                float x3 = fmaf(q[2], x2, -x1);
                a0 = fmaf(x0, s[0], a0);
                a1 = fmaf(x1, s[1], a1);
                a2 = fmaf(x2, s[2], a2);
                a3 = fmaf(x3, s[3], a3);
            }
            *(v4f*)&s1s[m * 256 + tl] = (v4f){
                fmaf(0.5f, a0, 0.5f * sum0[0]),
                fmaf(0.5f, a1, 0.5f * sum0[1]),
                fmaf(0.5f, a2, 0.5f * sum0[2]),
                fmaf(0.5f, a3, 0.5f * sum0[3])};
        }
    }
    __syncthreads();                 // all L1 reads of pp1/s0s complete

    // ---- phase C: stage L2+L3 params into dead pp1/s0s region ----
    for (int i = tid; i < 3120; i += 256) pp2[i] = g_P[2080 + i];
    __syncthreads();

    // ---- phase D: sum1 + layer 2 + fused layer 3 (8/8/7/7 of 30 m) ----
    float sum1[4] = {0.f, 0.f, 0.f, 0.f};
#pragma unroll
    for (int n = 0; n < 25; ++n) {
        const v4f s = *(const v4f*)&s1s[n * 256 + tl];
        sum1[0] += s[0]; sum1[1] += s[1]; sum1[2] += s[2]; sum1[3] += s[3];
    }
    float pw0 = 0.f, pw1 = 0.f, pw2 = 0.f, pw3 = 0.f;
    {
        const int mS = (w < 2) ? 8 * w : (16 + 7 * (w - 2));   // 0,8,16,23
        const int mC = (w < 2) ? 8 : 7;
        for (int i = 0; i < mC; ++i) {
            const int m = mS + i;
            const float* __restrict__ pb = &pp2[100 * m];
            float a0 = 0.f, a1 = 0.f, a2 = 0.f, a3 = 0.f;
#pragma unroll
            for (int n = 0; n < 25; ++n) {
                const v4f q = *(const v4f*)&pb[4 * n];           // uniform b128
                const v4f s = *(const v4f*)&s1s[n * 256 + tl];   // per-lane b128
                float x0 = sinp(fmaf(q[0], tv0, q[1]));
                float x1 = sinp(fmaf(q[0], tv1, q[1]));
                float x2 = fmaf(q[2], x1, -x0);
                float x3 = fmaf(q[2], x2, -x1);
                a0 = fmaf(x0, s[0], a0);
                a1 = fmaf(x1, s[1], a1);
                a2 = fmaf(x2, s[2], a2);
                a3 = fmaf(x3, s[3], a3);
            }
            const v4f q3 = *(const v4f*)&pp2[3000 + 4 * m];
            float y0 = sinp(fmaf(q3[0], tv0, q3[1]));
            float y1 = sinp(fmaf(q3[0], tv1, q3[1]));
            float y2 = fmaf(q3[2], y1, -y0);
            float y3 = fmaf(q3[2], y2, -y1);
            pw0 = fmaf(fmaf(0.5f, y0, 0.5f), fmaf(0.5f, a0, 0.5f * sum1[0]), pw0);
            pw1 = fmaf(fmaf(0.5f, y1, 0.5f), fmaf(0.5f, a1, 0.5f * sum1[1]), pw1);
            pw2 = fmaf(fmaf(0.5f, y2, 0.5f), fmaf(0.5f, a2, 0.5f * sum1[2]), pw2);
            pw3 = fmaf(fmaf(0.5f, y3, 0.5f), fmaf(0.5f, a3, 0.5f * sum1[3]), pw3);
        }
    }
    __syncthreads();                 // pp2/s1s reads done; shp region free
    *(v4f*)&shp[w * 256 + tl] = (v4f){pw0, pw1, pw2, pw3};
    __syncthreads();

    // ---- reduce across the 4 waves; wave w writes t_local [64w,64w+64) ----
    const int tlr = 64 * w + l;
    const float r = (shp[tlr] + shp[256 + tlr]) + (shp[512 + tlr] + shp[768 + tlr]);
    const int tt = tb + tlr;
    if (tt < T_TOTAL) out[tt] = r;
}

extern "C" void kernel_launch(void* const* d_in, const int* in_sizes, int n_in,
                              void* d_out, int out_size, void* d_ws, size_t ws_size,
                              hipStream_t stream) {
    (void)in_sizes; (void)n_in; (void)d_ws; (void)ws_size; (void)out_size;
    const float* A0    = (const float*)d_in[1];
    const float* w0    = (const float*)d_in[2];
    const float* phi0  = (const float*)d_in[3];
    const float* wc0   = (const float*)d_in[4];
    const float* phic0 = (const float*)d_in[5];
    const float* w1    = (const float*)d_in[6];
    const float* phi1  = (const float*)d_in[7];
    const float* wc1   = (const float*)d_in[8];
    const float* phic1 = (const float*)d_in[9];
    const float* w2    = (const float*)d_in[10];
    const float* phi2  = (const float*)d_in[11];
    const float* wc2   = (const float*)d_in[12];
    const float* phic2 = (const float*)d_in[13];
    const float* w3    = (const float*)d_in[14];
    const float* phi3  = (const float*)d_in[15];
    const float* wc3   = (const float*)d_in[16];
    const float* phic3 = (const float*)d_in[17];

    float* out = (float*)d_out;

    hipLaunchKernelGGL(prep_kernel, dim3(6), dim3(256), 0, stream,
                       A0, w0, phi0, wc0, phic0,
                       w1, phi1, wc1, phic1,
                       w2, phi2, wc2, phic2,
                       w3, phi3, wc3, phic3);

    const int grid = (T_TOTAL + 255) / 256;   // 782
    hipLaunchKernelGGL(wave_fused, dim3(grid), dim3(256), 0, stream, out);
}